// Round 8
// baseline (256.925 us; speedup 1.0000x reference)
//
#include <hip/hip_runtime.h>
#include <hip/hip_bf16.h>
#include <math.h>

#define NROWS 8192
#define DDIM  10000
#define NCLS  100
#define LISTCAP 512

#define KSPLIT 8
#define KS64   157            // 10048/64 k64-steps total
#define BM 128

#define SCORES_N (NROWS*NCLS)
#define NCHUNK8 1256          // k-octets, padded to 10048
#define BP_CHUNKS (NCHUNK8*128)

// ws layout in float (4B) units
#define WS_NORMCLS 0                                   // 128
#define WS_NRM     128                                 // KSPLIT*NROWS
#define WS_SCP     (WS_NRM + KSPLIT*NROWS)             // KSPLIT*NROWS*NCLS
#define WS_CNT_T   (WS_SCP + KSPLIT*SCORES_N)          // 128
#define WS_CNT_P   (WS_CNT_T + 128)                    // 128
#define WS_LIST_T  (WS_CNT_P + 128)                    // NCLS*LISTCAP
#define WS_LIST_P  (WS_LIST_T + NCLS*LISTCAP)          // NCLS*LISTCAP
#define WS_BPH     (WS_LIST_P + NCLS*LISTCAP)          // BP_CHUNKS*4 floats (8 f16 each)
#define WS_BPL     (WS_BPH + BP_CHUNKS*4)

typedef _Float16 f16;
typedef f16 f16x8 __attribute__((ext_vector_type(8)));
typedef float f32x4 __attribute__((ext_vector_type(4)));

#define SBAR()  __builtin_amdgcn_s_barrier()
#define SCHED() __builtin_amdgcn_sched_barrier(0)

// ---------------- Phase 0: class norms (+ zero list counters) ----------------
__global__ __launch_bounds__(256) void cls_norms(const float* __restrict__ cls,
                                                 float* __restrict__ ws)
{
    if (blockIdx.x == 0) ((int*)ws)[WS_CNT_T + threadIdx.x] = 0;  // 256 ints: CNT_T + CNT_P

    int c = blockIdx.x;
    const float* row = cls + (size_t)c * DDIM;
    float s = 0.f;
    for (int d = threadIdx.x; d < DDIM; d += 256) {
        float v = row[d];
        s = fmaf(v, v, s);
    }
    #pragma unroll
    for (int off = 32; off; off >>= 1) s += __shfl_xor(s, off, 64);
    __shared__ float red[4];
    int w = threadIdx.x >> 6, l = threadIdx.x & 63;
    if (l == 0) red[w] = s;
    __syncthreads();
    if (threadIdx.x == 0) {
        float t = red[0] + red[1] + red[2] + red[3];
        ws[WS_NORMCLS + c] = sqrtf(t);
    }
}

// ---------------- Phase 0b: class_hvs -> fp16 hi/lo, chunked [k8][col][8] ----------------
__global__ __launch_bounds__(256) void prep_b(const float* __restrict__ cls,
                                              float* __restrict__ ws)
{
    int c = blockIdx.x * 256 + threadIdx.x;
    if (c >= BP_CHUNKS) return;
    int col = c & 127, k8 = c >> 7;
    f16x8 hi, lo;
    #pragma unroll
    for (int j = 0; j < 8; ++j) {
        int k = k8 * 8 + j;
        float v = (col < NCLS && k < DDIM) ? cls[(size_t)col * DDIM + k] : 0.f;
        f16 h = (f16)v;
        hi[j] = h;
        lo[j] = (f16)(v - (float)h);
    }
    ((f16x8*)(ws + WS_BPH))[c] = hi;
    ((f16x8*)(ws + WS_BPL))[c] = lo;
}

// ---------------- Phase 1: MFMA GEMM, BK=64 per stage ----------------
// A: HBM -> per-lane frag regs -> convert (NO LDS). B: prepped hi/lo, regs -> LDS dbuf.
// grid (64, KSPLIT); 4 waves; wave w -> rows [r0+32w, +32) (mt=2), 112 live cols.
// Per step: 84 MFMA, ONE lgkm-drain + barrier.
__global__ __launch_bounds__(256, 2) void gemm_mfma(const float* __restrict__ enc,
                                                    float* __restrict__ ws)
{
    __shared__ f16 Bh[2][8*128*8], Bl[2][8*128*8];   // [buf][kg 0..7][colS][8], 16KB each buf

    int tid = threadIdx.x;
    int w = __builtin_amdgcn_readfirstlane(tid >> 6);
    int l = tid & 63;
    int lane15 = l & 15, lg = l >> 4;
    int r0 = blockIdx.x * BM;
    int ky = blockIdx.y;
    int s_beg = (KS64 * ky) / KSPLIT;
    int s_end = (KS64 * (ky + 1)) / KSPLIT;

    const float* aptr0 = enc + (size_t)(r0 + w * 32 + lane15) * DDIM;
    const float* aptr1 = aptr0 + (size_t)16 * DDIM;
    const f16* bph = (const f16*)(ws + WS_BPH);
    const f16* bpl = (const f16*)(ws + WS_BPL);

    f32x4 acc[2][7] = {};
    float nsq0 = 0.f, nsq1 = 0.f;

    float4 ar[8];                  // A(S): [row(2)][ksub(2)][pair(2)]
    f16x8 bsh[2][2], bsl[2][2];    // B(S) stage regs: [kg-idx][half]

    // per-lane k-offsets within a step: ksub0 -> octet lg, ksub1 -> octet 4+lg
    #define LOAD_A(S) do {                                               \
        int kA_ = (S) * 64 + lg * 8;                                     \
        int kB_ = kA_ + 32;                                              \
        int a0_ = (kA_ + 4 <= DDIM) ? kA_ : 0;                           \
        int a1_ = (kA_ + 8 <= DDIM) ? (kA_ + 4) : 0;                     \
        int b0_ = (kB_ + 4 <= DDIM) ? kB_ : 0;                           \
        int b1_ = (kB_ + 8 <= DDIM) ? (kB_ + 4) : 0;                     \
        ar[0] = *(const float4*)(aptr0 + a0_);                           \
        ar[1] = *(const float4*)(aptr0 + a1_);                           \
        ar[2] = *(const float4*)(aptr0 + b0_);                           \
        ar[3] = *(const float4*)(aptr0 + b1_);                           \
        ar[4] = *(const float4*)(aptr1 + a0_);                           \
        ar[5] = *(const float4*)(aptr1 + a1_);                           \
        ar[6] = *(const float4*)(aptr1 + b0_);                           \
        ar[7] = *(const float4*)(aptr1 + b1_);                           \
    } while (0)

    #define LOAD_B(S) do {                                               \
        _Pragma("unroll")                                                \
        for (int j_ = 0; j_ < 2; ++j_) {                                 \
            size_t base_ = ((size_t)((S) * 8 + 2 * w + j_) * 128) * 8;   \
            bsh[j_][0] = *(const f16x8*)(bph + base_ + (size_t)l * 8);   \
            bsh[j_][1] = *(const f16x8*)(bph + base_ + (size_t)(l + 64) * 8); \
            bsl[j_][0] = *(const f16x8*)(bpl + base_ + (size_t)l * 8);   \
            bsl[j_][1] = *(const f16x8*)(bpl + base_ + (size_t)(l + 64) * 8); \
        }                                                                \
    } while (0)

    LOAD_A(s_beg);
    LOAD_B(s_beg);

    for (int S = s_beg; S < s_end; ++S) {
        int cur = S & 1;

        // 1. convert A(S) -> hi/lo frags: [row][ksub] (+ tail mask + norm accum)
        f16x8 ah[2][2], al[2][2];
        #pragma unroll
        for (int r = 0; r < 2; ++r) {
            float& nsq = r ? nsq1 : nsq0;
            #pragma unroll
            for (int ks = 0; ks < 2; ++ks) {
                float4 p0 = ar[r * 4 + ks * 2], p1 = ar[r * 4 + ks * 2 + 1];
                float v[8] = {p0.x, p0.y, p0.z, p0.w, p1.x, p1.y, p1.z, p1.w};
                int kb = S * 64 + ks * 32 + lg * 8;
                if (kb + 8 > DDIM) {
                    #pragma unroll
                    for (int j = 0; j < 8; ++j) if (kb + j >= DDIM) v[j] = 0.f;
                }
                #pragma unroll
                for (int j = 0; j < 8; ++j) {
                    f16 h = (f16)v[j];
                    ah[r][ks][j] = h;
                    al[r][ks][j] = (f16)(v[j] - (float)h);
                    nsq = fmaf(v[j], v[j], nsq);
                }
            }
        }

        // 2. ds_write B(S) -> buf[cur], XOR-swizzled slots (wave w: kg 2w, 2w+1)
        #pragma unroll
        for (int j = 0; j < 2; ++j) {
            int kg = 2 * w + j;
            int s0 = kg * 128 + (l ^ kg);
            int s1 = kg * 128 + ((l + 64) ^ kg);
            *(f16x8*)&Bh[cur][s0 * 8] = bsh[j][0];
            *(f16x8*)&Bh[cur][s1 * 8] = bsh[j][1];
            *(f16x8*)&Bl[cur][s0 * 8] = bsl[j][0];
            *(f16x8*)&Bl[cur][s1 * 8] = bsl[j][1];
        }

        // 3. prefetch A(S+1), B(S+1) (clamped reload at the end, discarded)
        {
            int Sn = (S + 1 < s_end) ? (S + 1) : S;
            LOAD_A(Sn);
            LOAD_B(Sn);
        }

        // 4. fence: B(S) ds_writes visible to all waves
        SCHED();
        asm volatile("s_waitcnt lgkmcnt(0)" ::: "memory");
        SBAR();
        SCHED();

        // 5. read B frags + 84 MFMA (cols 0..111; nt=7 padding skipped)
        #pragma unroll
        for (int ks = 0; ks < 2; ++ks) {
            int kg = ks * 4 + lg;
            #pragma unroll
            for (int nt = 0; nt < 7; ++nt) {
                int colS = (nt * 16 + lane15) ^ kg;
                f16x8 bh = *(const f16x8*)&Bh[cur][(kg * 128 + colS) * 8];
                f16x8 bl = *(const f16x8*)&Bl[cur][(kg * 128 + colS) * 8];
                acc[0][nt] = __builtin_amdgcn_mfma_f32_16x16x32_f16(ah[0][ks], bh, acc[0][nt], 0, 0, 0);
                acc[0][nt] = __builtin_amdgcn_mfma_f32_16x16x32_f16(al[0][ks], bh, acc[0][nt], 0, 0, 0);
                acc[0][nt] = __builtin_amdgcn_mfma_f32_16x16x32_f16(ah[0][ks], bl, acc[0][nt], 0, 0, 0);
                acc[1][nt] = __builtin_amdgcn_mfma_f32_16x16x32_f16(ah[1][ks], bh, acc[1][nt], 0, 0, 0);
                acc[1][nt] = __builtin_amdgcn_mfma_f32_16x16x32_f16(al[1][ks], bh, acc[1][nt], 0, 0, 0);
                acc[1][nt] = __builtin_amdgcn_mfma_f32_16x16x32_f16(ah[1][ks], bl, acc[1][nt], 0, 0, 0);
            }
        }
    }

    // ---- epilogue: partial scores (C layout: col=lane15, row=lg*4+j) ----
    float* scp = ws + WS_SCP + (size_t)ky * SCORES_N;
    #pragma unroll
    for (int mt = 0; mt < 2; ++mt) {
        #pragma unroll
        for (int nt = 0; nt < 7; ++nt) {
            int gcol = nt * 16 + lane15;
            if (gcol < NCLS) {
                #pragma unroll
                for (int j = 0; j < 4; ++j) {
                    int grow = r0 + w * 32 + mt * 16 + lg * 4 + j;
                    scp[(size_t)grow * NCLS + gcol] = acc[mt][nt][j];
                }
            }
        }
    }

    // ---- row-norm partials: reduce across lg (lanes l, l+16, l+32, l+48) ----
    nsq0 += __shfl_xor(nsq0, 16, 64);
    nsq0 += __shfl_xor(nsq0, 32, 64);
    nsq1 += __shfl_xor(nsq1, 16, 64);
    nsq1 += __shfl_xor(nsq1, 32, 64);
    if (l < 16) {
        ws[WS_NRM + (size_t)ky * NROWS + r0 + w * 32 + l] = nsq0;
        ws[WS_NRM + (size_t)ky * NROWS + r0 + w * 32 + 16 + l] = nsq1;
    }
}

// ---------------- Phase 2: finalize scores, argmax, build class lists ----------------
__global__ __launch_bounds__(256) void finalize(const int* __restrict__ targets,
                                                float* __restrict__ out,
                                                float* __restrict__ ws)
{
    int w = threadIdx.x >> 6, l = threadIdx.x & 63;
    int row = blockIdx.x * 4 + w;
    const float* scp = ws + WS_SCP;

    float n2 = 0.f;
    #pragma unroll
    for (int ky = 0; ky < KSPLIT; ++ky) n2 += ws[WS_NRM + (size_t)ky * NROWS + row];
    float ne = sqrtf(n2);

    float best; int bi;
    {
        int c = l;
        float dsum = 0.f;
        #pragma unroll
        for (int ky = 0; ky < KSPLIT; ++ky)
            dsum += scp[(size_t)ky * SCORES_N + (size_t)row * NCLS + c];
        float s = dsum / (ne * ws[WS_NORMCLS + c]);
        out[(size_t)row * NCLS + c] = s;
        best = s; bi = c;
    }
    if (l + 64 < NCLS) {
        int c = l + 64;
        float dsum = 0.f;
        #pragma unroll
        for (int ky = 0; ky < KSPLIT; ++ky)
            dsum += scp[(size_t)ky * SCORES_N + (size_t)row * NCLS + c];
        float s = dsum / (ne * ws[WS_NORMCLS + c]);
        out[(size_t)row * NCLS + c] = s;
        if (s > best) { best = s; bi = c; }   // ties keep smaller index
    }
    #pragma unroll
    for (int off = 32; off; off >>= 1) {
        float ov = __shfl_xor(best, off, 64);
        int   oi = __shfl_xor(bi, off, 64);
        if (ov > best || (ov == best && oi < bi)) { best = ov; bi = oi; }
    }
    if (l == 0) {
        int tgt = targets[row];
        if (tgt != bi) {
            int* wsi = (int*)ws;
            int p1 = atomicAdd(wsi + WS_CNT_T + tgt, 1);
            if (p1 < LISTCAP) wsi[WS_LIST_T + tgt * LISTCAP + p1] = row;
            int p2 = atomicAdd(wsi + WS_CNT_P + bi, 1);
            if (p2 < LISTCAP) wsi[WS_LIST_P + bi * LISTCAP + p2] = row;
        }
    }
}

// ---------------- Phase 2b: sort class lists by row index (bitonic, LDS) ----------------
// Sorted lists => the two consumer blocks of a row stream it at ~the same time
// => second read hits L2/L3. Deterministic (fixed sorted order).
__global__ __launch_bounds__(256) void sort_lists(float* __restrict__ ws)
{
    __shared__ int buf[LISTCAP];
    int* wsi = (int*)ws;
    int c = blockIdx.x >> 1;
    int which = blockIdx.x & 1;
    int* list = wsi + (which ? WS_LIST_P + c * LISTCAP : WS_LIST_T + c * LISTCAP);
    int n = wsi[(which ? WS_CNT_P : WS_CNT_T) + c];
    n = n < LISTCAP ? n : LISTCAP;

    #pragma unroll
    for (int t = threadIdx.x; t < LISTCAP; t += 256)
        buf[t] = (t < n) ? list[t] : 0x7FFFFFFF;
    __syncthreads();

    for (int k = 2; k <= LISTCAP; k <<= 1) {
        for (int j = k >> 1; j > 0; j >>= 1) {
            #pragma unroll
            for (int t = threadIdx.x; t < LISTCAP; t += 256) {
                int ixj = t ^ j;
                if (ixj > t) {
                    int a = buf[t], b = buf[ixj];
                    bool up = ((t & k) == 0);
                    if ((a > b) == up) { buf[t] = b; buf[ixj] = a; }
                }
            }
            __syncthreads();
        }
    }

    for (int t = threadIdx.x; t < n; t += 256) list[t] = buf[t];
}

// ---------------- Phase 3: perceptron update (sorted lists, LDS-staged) ----------------
__global__ __launch_bounds__(256) void update(const float* __restrict__ enc,
                                              const float* __restrict__ cls,
                                              float* __restrict__ out,
                                              const float* __restrict__ ws)
{
    __shared__ int lstT[LISTCAP], lstP[LISTCAP];
    int c = blockIdx.x;
    const int* wsi = (const int*)ws;
    int nt = wsi[WS_CNT_T + c]; nt = nt < LISTCAP ? nt : LISTCAP;
    int np = wsi[WS_CNT_P + c]; np = np < LISTCAP ? np : LISTCAP;
    for (int i = threadIdx.x; i < nt; i += 256) lstT[i] = wsi[WS_LIST_T + c * LISTCAP + i];
    for (int i = threadIdx.x; i < np; i += 256) lstP[i] = wsi[WS_LIST_P + c * LISTCAP + i];
    __syncthreads();

    int d4 = blockIdx.y * 256 + threadIdx.x;     // float4 index; DDIM/4 = 2500
    if (d4 >= DDIM / 4) return;
    const float4* enc4 = (const float4*)enc;
    const float4* cls4 = (const float4*)cls;

    float4 ac0 = make_float4(0.f, 0.f, 0.f, 0.f);
    float4 ac1 = make_float4(0.f, 0.f, 0.f, 0.f);
    int i = 0;
    #pragma unroll 2
    for (; i + 2 <= nt; i += 2) {
        float4 e0 = enc4[(size_t)lstT[i] * (DDIM / 4) + d4];
        float4 e1 = enc4[(size_t)lstT[i + 1] * (DDIM / 4) + d4];
        ac0.x += e0.x; ac0.y += e0.y; ac0.z += e0.z; ac0.w += e0.w;
        ac1.x += e1.x; ac1.y += e1.y; ac1.z += e1.z; ac1.w += e1.w;
    }
    if (i < nt) {
        float4 e0 = enc4[(size_t)lstT[i] * (DDIM / 4) + d4];
        ac0.x += e0.x; ac0.y += e0.y; ac0.z += e0.z; ac0.w += e0.w;
    }
    i = 0;
    #pragma unroll 2
    for (; i + 2 <= np; i += 2) {
        float4 e0 = enc4[(size_t)lstP[i] * (DDIM / 4) + d4];
        float4 e1 = enc4[(size_t)lstP[i + 1] * (DDIM / 4) + d4];
        ac0.x -= e0.x; ac0.y -= e0.y; ac0.z -= e0.z; ac0.w -= e0.w;
        ac1.x -= e1.x; ac1.y -= e1.y; ac1.z -= e1.z; ac1.w -= e1.w;
    }
    if (i < np) {
        float4 e0 = enc4[(size_t)lstP[i] * (DDIM / 4) + d4];
        ac0.x -= e0.x; ac0.y -= e0.y; ac0.z -= e0.z; ac0.w -= e0.w;
    }

    float4 cv = cls4[(size_t)c * (DDIM / 4) + d4];
    float4 r = make_float4(cv.x + ac0.x + ac1.x, cv.y + ac0.y + ac1.y,
                           cv.z + ac0.z + ac1.z, cv.w + ac0.w + ac1.w);
    ((float4*)out)[SCORES_N / 4 + (size_t)c * (DDIM / 4) + d4] = r;
}

// ---------------- launch ----------------
extern "C" void kernel_launch(void* const* d_in, const int* in_sizes, int n_in,
                              void* d_out, int out_size, void* d_ws, size_t ws_size,
                              hipStream_t stream)
{
    const float* enc = (const float*)d_in[0];
    const float* cls = (const float*)d_in[1];
    const int*   tgt = (const int*)d_in[2];
    float* out = (float*)d_out;
    float* ws  = (float*)d_ws;

    cls_norms<<<NCLS, 256, 0, stream>>>(cls, ws);
    prep_b<<<(BP_CHUNKS + 255) / 256, 256, 0, stream>>>(cls, ws);

    dim3 g1(NROWS / BM, KSPLIT);
    gemm_mfma<<<g1, 256, 0, stream>>>(enc, ws);

    finalize<<<NROWS / 4, 256, 0, stream>>>(tgt, out, ws);

    sort_lists<<<NCLS * 2, 256, 0, stream>>>(ws);

    dim3 g3(NCLS, (DDIM / 4 + 255) / 256);
    update<<<g3, 256, 0, stream>>>(enc, cls, out, ws);
}

// Round 9
// 241.242 us; speedup vs baseline: 1.0650x; 1.0650x over previous
//
#include <hip/hip_runtime.h>
#include <hip/hip_bf16.h>
#include <math.h>

#define NROWS 8192
#define DDIM  10000
#define NCLS  100
#define LISTCAP 512

#define KSPLIT 8
#define KS64   157            // 10048/64 k64-steps total
#define BM 128

#define SCORES_N (NROWS*NCLS)
#define NCHUNK8 1256          // k-octets, padded to 10048
#define BP_CHUNKS (NCHUNK8*128)
#define PREPB_BLOCKS ((BP_CHUNKS + 255) / 256)

// ws layout in float (4B) units
#define WS_NORMCLS 0                                   // 128
#define WS_NRM     128                                 // KSPLIT*NROWS
#define WS_SCP     (WS_NRM + KSPLIT*NROWS)             // KSPLIT*NROWS*NCLS
#define WS_CNT_T   (WS_SCP + KSPLIT*SCORES_N)          // 128
#define WS_CNT_P   (WS_CNT_T + 128)                    // 128
#define WS_LIST_T  (WS_CNT_P + 128)                    // NCLS*LISTCAP
#define WS_LIST_P  (WS_LIST_T + NCLS*LISTCAP)          // NCLS*LISTCAP
#define WS_BPH     (WS_LIST_P + NCLS*LISTCAP)          // BP_CHUNKS*4 floats (8 f16 each)
#define WS_BPL     (WS_BPH + BP_CHUNKS*4)

typedef _Float16 f16;
typedef f16 f16x8 __attribute__((ext_vector_type(8)));
typedef float f32x4 __attribute__((ext_vector_type(4)));

#define SBAR()  __builtin_amdgcn_s_barrier()
#define SCHED() __builtin_amdgcn_sched_barrier(0)

// ---------------- Phase 0 (fused): class norms + counter zero + B prep ----------------
// blocks [0, NCLS): norms (+ block 0 zeroes counters); blocks [NCLS, NCLS+PREPB_BLOCKS): prep_b
__global__ __launch_bounds__(256) void prep(const float* __restrict__ cls,
                                            float* __restrict__ ws)
{
    int bx = blockIdx.x;
    if (bx < NCLS) {
        if (bx == 0) ((int*)ws)[WS_CNT_T + threadIdx.x] = 0;  // 256 ints: CNT_T + CNT_P
        int c = bx;
        const float* row = cls + (size_t)c * DDIM;
        float s = 0.f;
        for (int d = threadIdx.x; d < DDIM; d += 256) {
            float v = row[d];
            s = fmaf(v, v, s);
        }
        #pragma unroll
        for (int off = 32; off; off >>= 1) s += __shfl_xor(s, off, 64);
        __shared__ float red[4];
        int w = threadIdx.x >> 6, l = threadIdx.x & 63;
        if (l == 0) red[w] = s;
        __syncthreads();
        if (threadIdx.x == 0) {
            float t = red[0] + red[1] + red[2] + red[3];
            ws[WS_NORMCLS + c] = sqrtf(t);
        }
    } else {
        int c = (bx - NCLS) * 256 + threadIdx.x;
        if (c >= BP_CHUNKS) return;
        int col = c & 127, k8 = c >> 7;
        f16x8 hi, lo;
        #pragma unroll
        for (int j = 0; j < 8; ++j) {
            int k = k8 * 8 + j;
            float v = (col < NCLS && k < DDIM) ? cls[(size_t)col * DDIM + k] : 0.f;
            f16 h = (f16)v;
            hi[j] = h;
            lo[j] = (f16)(v - (float)h);
        }
        ((f16x8*)(ws + WS_BPH))[c] = hi;
        ((f16x8*)(ws + WS_BPL))[c] = lo;
    }
}

// ---------------- Phase 1: MFMA GEMM, BK=64 per stage ----------------
// A: HBM -> per-lane frag regs -> convert (NO LDS). B: prepped hi/lo, regs -> LDS dbuf.
// grid (64, KSPLIT); 4 waves; wave w -> rows [r0+32w, +32) (mt=2), 112 live cols.
// Per step: 84 MFMA, ONE lgkm-drain + barrier; 256 B per A-row per step.
__global__ __launch_bounds__(256, 2) void gemm_mfma(const float* __restrict__ enc,
                                                    float* __restrict__ ws)
{
    __shared__ f16 Bh[2][8*128*8], Bl[2][8*128*8];   // [buf][kg 0..7][colS][8], 16KB each buf

    int tid = threadIdx.x;
    int w = __builtin_amdgcn_readfirstlane(tid >> 6);
    int l = tid & 63;
    int lane15 = l & 15, lg = l >> 4;
    int r0 = blockIdx.x * BM;
    int ky = blockIdx.y;
    int s_beg = (KS64 * ky) / KSPLIT;
    int s_end = (KS64 * (ky + 1)) / KSPLIT;

    const float* aptr0 = enc + (size_t)(r0 + w * 32 + lane15) * DDIM;
    const float* aptr1 = aptr0 + (size_t)16 * DDIM;
    const f16* bph = (const f16*)(ws + WS_BPH);
    const f16* bpl = (const f16*)(ws + WS_BPL);

    f32x4 acc[2][7] = {};
    float nsq0 = 0.f, nsq1 = 0.f;

    float4 ar[8];                  // A(S): [row(2)][ksub(2)][pair(2)]
    f16x8 bsh[2][2], bsl[2][2];    // B(S) stage regs: [kg-idx][half]

    #define LOAD_A(S) do {                                               \
        int kA_ = (S) * 64 + lg * 8;                                     \
        int kB_ = kA_ + 32;                                              \
        int a0_ = (kA_ + 4 <= DDIM) ? kA_ : 0;                           \
        int a1_ = (kA_ + 8 <= DDIM) ? (kA_ + 4) : 0;                     \
        int b0_ = (kB_ + 4 <= DDIM) ? kB_ : 0;                           \
        int b1_ = (kB_ + 8 <= DDIM) ? (kB_ + 4) : 0;                     \
        ar[0] = *(const float4*)(aptr0 + a0_);                           \
        ar[1] = *(const float4*)(aptr0 + a1_);                           \
        ar[2] = *(const float4*)(aptr0 + b0_);                           \
        ar[3] = *(const float4*)(aptr0 + b1_);                           \
        ar[4] = *(const float4*)(aptr1 + a0_);                           \
        ar[5] = *(const float4*)(aptr1 + a1_);                           \
        ar[6] = *(const float4*)(aptr1 + b0_);                           \
        ar[7] = *(const float4*)(aptr1 + b1_);                           \
    } while (0)

    #define LOAD_B(S) do {                                               \
        _Pragma("unroll")                                                \
        for (int j_ = 0; j_ < 2; ++j_) {                                 \
            size_t base_ = ((size_t)((S) * 8 + 2 * w + j_) * 128) * 8;   \
            bsh[j_][0] = *(const f16x8*)(bph + base_ + (size_t)l * 8);   \
            bsh[j_][1] = *(const f16x8*)(bph + base_ + (size_t)(l + 64) * 8); \
            bsl[j_][0] = *(const f16x8*)(bpl + base_ + (size_t)l * 8);   \
            bsl[j_][1] = *(const f16x8*)(bpl + base_ + (size_t)(l + 64) * 8); \
        }                                                                \
    } while (0)

    LOAD_A(s_beg);
    LOAD_B(s_beg);

    for (int S = s_beg; S < s_end; ++S) {
        int cur = S & 1;

        // 1. convert A(S) -> hi/lo frags: [row][ksub] (+ tail mask + norm accum)
        f16x8 ah[2][2], al[2][2];
        #pragma unroll
        for (int r = 0; r < 2; ++r) {
            float& nsq = r ? nsq1 : nsq0;
            #pragma unroll
            for (int ks = 0; ks < 2; ++ks) {
                float4 p0 = ar[r * 4 + ks * 2], p1 = ar[r * 4 + ks * 2 + 1];
                float v[8] = {p0.x, p0.y, p0.z, p0.w, p1.x, p1.y, p1.z, p1.w};
                int kb = S * 64 + ks * 32 + lg * 8;
                if (kb + 8 > DDIM) {
                    #pragma unroll
                    for (int j = 0; j < 8; ++j) if (kb + j >= DDIM) v[j] = 0.f;
                }
                #pragma unroll
                for (int j = 0; j < 8; ++j) {
                    f16 h = (f16)v[j];
                    ah[r][ks][j] = h;
                    al[r][ks][j] = (f16)(v[j] - (float)h);
                    nsq = fmaf(v[j], v[j], nsq);
                }
            }
        }

        // 2. ds_write B(S) -> buf[cur], XOR-swizzled slots (wave w: kg 2w, 2w+1)
        #pragma unroll
        for (int j = 0; j < 2; ++j) {
            int kg = 2 * w + j;
            int s0 = kg * 128 + (l ^ kg);
            int s1 = kg * 128 + ((l + 64) ^ kg);
            *(f16x8*)&Bh[cur][s0 * 8] = bsh[j][0];
            *(f16x8*)&Bh[cur][s1 * 8] = bsh[j][1];
            *(f16x8*)&Bl[cur][s0 * 8] = bsl[j][0];
            *(f16x8*)&Bl[cur][s1 * 8] = bsl[j][1];
        }

        // 3. prefetch A(S+1), B(S+1) (clamped reload at the end, discarded)
        {
            int Sn = (S + 1 < s_end) ? (S + 1) : S;
            LOAD_A(Sn);
            LOAD_B(Sn);
        }

        // 4. fence: B(S) ds_writes visible to all waves
        SCHED();
        asm volatile("s_waitcnt lgkmcnt(0)" ::: "memory");
        SBAR();
        SCHED();

        // 5. read B frags + 84 MFMA (cols 0..111; nt=7 padding skipped)
        #pragma unroll
        for (int ks = 0; ks < 2; ++ks) {
            int kg = ks * 4 + lg;
            #pragma unroll
            for (int nt = 0; nt < 7; ++nt) {
                int colS = (nt * 16 + lane15) ^ kg;
                f16x8 bh = *(const f16x8*)&Bh[cur][(kg * 128 + colS) * 8];
                f16x8 bl = *(const f16x8*)&Bl[cur][(kg * 128 + colS) * 8];
                acc[0][nt] = __builtin_amdgcn_mfma_f32_16x16x32_f16(ah[0][ks], bh, acc[0][nt], 0, 0, 0);
                acc[0][nt] = __builtin_amdgcn_mfma_f32_16x16x32_f16(al[0][ks], bh, acc[0][nt], 0, 0, 0);
                acc[0][nt] = __builtin_amdgcn_mfma_f32_16x16x32_f16(ah[0][ks], bl, acc[0][nt], 0, 0, 0);
                acc[1][nt] = __builtin_amdgcn_mfma_f32_16x16x32_f16(ah[1][ks], bh, acc[1][nt], 0, 0, 0);
                acc[1][nt] = __builtin_amdgcn_mfma_f32_16x16x32_f16(al[1][ks], bh, acc[1][nt], 0, 0, 0);
                acc[1][nt] = __builtin_amdgcn_mfma_f32_16x16x32_f16(ah[1][ks], bl, acc[1][nt], 0, 0, 0);
            }
        }
    }

    // ---- epilogue: partial scores (C layout: col=lane15, row=lg*4+j) ----
    float* scp = ws + WS_SCP + (size_t)ky * SCORES_N;
    #pragma unroll
    for (int mt = 0; mt < 2; ++mt) {
        #pragma unroll
        for (int nt = 0; nt < 7; ++nt) {
            int gcol = nt * 16 + lane15;
            if (gcol < NCLS) {
                #pragma unroll
                for (int j = 0; j < 4; ++j) {
                    int grow = r0 + w * 32 + mt * 16 + lg * 4 + j;
                    scp[(size_t)grow * NCLS + gcol] = acc[mt][nt][j];
                }
            }
        }
    }

    // ---- row-norm partials: reduce across lg (lanes l, l+16, l+32, l+48) ----
    nsq0 += __shfl_xor(nsq0, 16, 64);
    nsq0 += __shfl_xor(nsq0, 32, 64);
    nsq1 += __shfl_xor(nsq1, 16, 64);
    nsq1 += __shfl_xor(nsq1, 32, 64);
    if (l < 16) {
        ws[WS_NRM + (size_t)ky * NROWS + r0 + w * 32 + l] = nsq0;
        ws[WS_NRM + (size_t)ky * NROWS + r0 + w * 32 + 16 + l] = nsq1;
    }
}

// ---------------- Phase 2: finalize scores, argmax, build class lists ----------------
__global__ __launch_bounds__(256) void finalize(const int* __restrict__ targets,
                                                float* __restrict__ out,
                                                float* __restrict__ ws)
{
    int w = threadIdx.x >> 6, l = threadIdx.x & 63;
    int row = blockIdx.x * 4 + w;
    const float* scp = ws + WS_SCP;

    float n2 = 0.f;
    #pragma unroll
    for (int ky = 0; ky < KSPLIT; ++ky) n2 += ws[WS_NRM + (size_t)ky * NROWS + row];
    float ne = sqrtf(n2);

    float best; int bi;
    {
        int c = l;
        float dsum = 0.f;
        #pragma unroll
        for (int ky = 0; ky < KSPLIT; ++ky)
            dsum += scp[(size_t)ky * SCORES_N + (size_t)row * NCLS + c];
        float s = dsum / (ne * ws[WS_NORMCLS + c]);
        out[(size_t)row * NCLS + c] = s;
        best = s; bi = c;
    }
    if (l + 64 < NCLS) {
        int c = l + 64;
        float dsum = 0.f;
        #pragma unroll
        for (int ky = 0; ky < KSPLIT; ++ky)
            dsum += scp[(size_t)ky * SCORES_N + (size_t)row * NCLS + c];
        float s = dsum / (ne * ws[WS_NORMCLS + c]);
        out[(size_t)row * NCLS + c] = s;
        if (s > best) { best = s; bi = c; }   // ties keep smaller index
    }
    #pragma unroll
    for (int off = 32; off; off >>= 1) {
        float ov = __shfl_xor(best, off, 64);
        int   oi = __shfl_xor(bi, off, 64);
        if (ov > best || (ov == best && oi < bi)) { best = ov; bi = oi; }
    }
    if (l == 0) {
        int tgt = targets[row];
        if (tgt != bi) {
            int* wsi = (int*)ws;
            int p1 = atomicAdd(wsi + WS_CNT_T + tgt, 1);
            if (p1 < LISTCAP) wsi[WS_LIST_T + tgt * LISTCAP + p1] = row;
            int p2 = atomicAdd(wsi + WS_CNT_P + bi, 1);
            if (p2 < LISTCAP) wsi[WS_LIST_P + bi * LISTCAP + p2] = row;
        }
    }
}

// ---------------- Phase 3: perceptron update (LDS-staged lists, class-fast cohort) ----------------
__global__ __launch_bounds__(256) void update(const float* __restrict__ enc,
                                              const float* __restrict__ cls,
                                              float* __restrict__ out,
                                              const float* __restrict__ ws)
{
    __shared__ int lstT[LISTCAP], lstP[LISTCAP];
    int c = blockIdx.x;
    const int* wsi = (const int*)ws;
    int nt = wsi[WS_CNT_T + c]; nt = nt < LISTCAP ? nt : LISTCAP;
    int np = wsi[WS_CNT_P + c]; np = np < LISTCAP ? np : LISTCAP;
    for (int i = threadIdx.x; i < nt; i += 256) lstT[i] = wsi[WS_LIST_T + c * LISTCAP + i];
    for (int i = threadIdx.x; i < np; i += 256) lstP[i] = wsi[WS_LIST_P + c * LISTCAP + i];
    __syncthreads();

    int d4 = blockIdx.y * 256 + threadIdx.x;     // float4 index; DDIM/4 = 2500
    if (d4 >= DDIM / 4) return;
    const float4* enc4 = (const float4*)enc;
    const float4* cls4 = (const float4*)cls;

    float4 ac0 = make_float4(0.f, 0.f, 0.f, 0.f);
    float4 ac1 = make_float4(0.f, 0.f, 0.f, 0.f);
    int i = 0;
    #pragma unroll 2
    for (; i + 2 <= nt; i += 2) {
        float4 e0 = enc4[(size_t)lstT[i] * (DDIM / 4) + d4];
        float4 e1 = enc4[(size_t)lstT[i + 1] * (DDIM / 4) + d4];
        ac0.x += e0.x; ac0.y += e0.y; ac0.z += e0.z; ac0.w += e0.w;
        ac1.x += e1.x; ac1.y += e1.y; ac1.z += e1.z; ac1.w += e1.w;
    }
    if (i < nt) {
        float4 e0 = enc4[(size_t)lstT[i] * (DDIM / 4) + d4];
        ac0.x += e0.x; ac0.y += e0.y; ac0.z += e0.z; ac0.w += e0.w;
    }
    i = 0;
    #pragma unroll 2
    for (; i + 2 <= np; i += 2) {
        float4 e0 = enc4[(size_t)lstP[i] * (DDIM / 4) + d4];
        float4 e1 = enc4[(size_t)lstP[i + 1] * (DDIM / 4) + d4];
        ac0.x -= e0.x; ac0.y -= e0.y; ac0.z -= e0.z; ac0.w -= e0.w;
        ac1.x -= e1.x; ac1.y -= e1.y; ac1.z -= e1.z; ac1.w -= e1.w;
    }
    if (i < np) {
        float4 e0 = enc4[(size_t)lstP[i] * (DDIM / 4) + d4];
        ac0.x -= e0.x; ac0.y -= e0.y; ac0.z -= e0.z; ac0.w -= e0.w;
    }

    float4 cv = cls4[(size_t)c * (DDIM / 4) + d4];
    float4 r = make_float4(cv.x + ac0.x + ac1.x, cv.y + ac0.y + ac1.y,
                           cv.z + ac0.z + ac1.z, cv.w + ac0.w + ac1.w);
    ((float4*)out)[SCORES_N / 4 + (size_t)c * (DDIM / 4) + d4] = r;
}

// ---------------- launch ----------------
extern "C" void kernel_launch(void* const* d_in, const int* in_sizes, int n_in,
                              void* d_out, int out_size, void* d_ws, size_t ws_size,
                              hipStream_t stream)
{
    const float* enc = (const float*)d_in[0];
    const float* cls = (const float*)d_in[1];
    const int*   tgt = (const int*)d_in[2];
    float* out = (float*)d_out;
    float* ws  = (float*)d_ws;

    prep<<<NCLS + PREPB_BLOCKS, 256, 0, stream>>>(cls, ws);

    dim3 g1(NROWS / BM, KSPLIT);
    gemm_mfma<<<g1, 256, 0, stream>>>(enc, ws);

    finalize<<<NROWS / 4, 256, 0, stream>>>(tgt, out, ws);

    dim3 g3(NCLS, (DDIM / 4 + 255) / 256);
    update<<<g3, 256, 0, stream>>>(enc, cls, out, ws);
}